// Round 4
// baseline (36.941 us; speedup 1.0000x reference)
//
#include <hip/hip_runtime.h>

#define DIM 256
#define BATCH 16384
#define MARGIN 1.0f
#define EPSV 1e-6f

// 2 waves per pair (pos wave + neg wave), 4 waves per 256-thread block
// -> 2 pairs per block -> BATCH/2 blocks.
#define NBLOCKS (BATCH / 2)

typedef float fx4 __attribute__((ext_vector_type(4)));

__device__ __forceinline__ fx4 nt_load4(const void* p) {
    return __builtin_nontemporal_load((const fx4*)p);
}

__device__ __forceinline__ float dot4(fx4 a, fx4 b) {
    return a.x * b.x + a.y * b.y + a.z * b.z + a.w * b.w;
}

// Wave g scores one triple: pair = g>>1, side = g&1 (0=pos, 1=neg).
// Lane l owns elements [4l, 4l+4). Forced to <=64 VGPR for 8 waves/SIMD.
__global__ __launch_bounds__(256, 8) void transd_score_kernel(
    const int* __restrict__ pos_x, const int* __restrict__ neg_x,
    const float* __restrict__ ent, const float* __restrict__ entm,
    const float* __restrict__ rel, const float* __restrict__ relm,
    float* __restrict__ partial) {
    const int gwave = (blockIdx.x * blockDim.x + threadIdx.x) >> 6;
    const int lane  = threadIdx.x & 63;
    const int pair  = gwave >> 1;
    const int* __restrict__ tri = (gwave & 1) ? neg_x : pos_x;

    const int h_idx = tri[pair * 3 + 0];
    const int r_idx = tri[pair * 3 + 1];
    const int t_idx = tri[pair * 3 + 2];

    // 32-bit byte offsets, shared between the paired tables (SGPR base + VGPR offset).
    const unsigned lb   = (unsigned)lane << 4;          // lane*16 bytes
    const unsigned hoff = ((unsigned)h_idx << 10) + lb; // row*1024 + lane*16
    const unsigned toff = ((unsigned)t_idx << 10) + lb;
    const unsigned roff = ((unsigned)r_idx << 10) + lb;

    // Entity rows: nontemporal (streaming, no reuse). Relation rows: cached (2MB, L2-hot).
    fx4 hv  = nt_load4((const char*)ent  + hoff);
    fx4 hpv = nt_load4((const char*)entm + hoff);
    fx4 tv  = nt_load4((const char*)ent  + toff);
    fx4 tpv = nt_load4((const char*)entm + toff);
    fx4 rv  = *(const fx4*)((const char*)rel  + roff);
    fx4 rpv = *(const fx4*)((const char*)relm + roff);

    // alpha = <h,hp>, beta = <t,tp>, interleaved shuffle chains.
    float a = dot4(hv, hpv);
    float b = dot4(tv, tpv);
#pragma unroll
    for (int m = 32; m > 0; m >>= 1) {
        a += __shfl_xor(a, m, 64);
        b += __shfl_xor(b, m, 64);
    }
    const float ab = a - b;

    // diff = rp*(alpha-beta) + h + r - t + EPS
    float dx = rpv.x * ab + hv.x + rv.x - tv.x + EPSV;
    float dy = rpv.y * ab + hv.y + rv.y - tv.y + EPSV;
    float dz = rpv.z * ab + hv.z + rv.z - tv.z + EPSV;
    float dw = rpv.w * ab + hv.w + rv.w - tv.w + EPSV;

    float ss = dx * dx + dy * dy + dz * dz + dw * dw;
#pragma unroll
    for (int m = 32; m > 0; m >>= 1) ss += __shfl_xor(ss, m, 64);

    // Pair pos/neg through LDS: waves {0,1} = pair A, {2,3} = pair B.
    __shared__ float sc[4];
    if (lane == 0) sc[threadIdx.x >> 6] = sqrtf(ss);
    __syncthreads();
    if (threadIdx.x == 0) {
        float va = sc[0] - sc[1] + MARGIN;
        float vb = sc[2] - sc[3] + MARGIN;
        partial[blockIdx.x] = (va > 0.0f ? va : 0.0f) + (vb > 0.0f ? vb : 0.0f);
    }
}

// Deterministic single-block reduction of NBLOCKS floats -> out[0] = sum / BATCH.
__global__ __launch_bounds__(256) void reduce_kernel(const float* __restrict__ partial,
                                                     float* __restrict__ out) {
    const int lane = threadIdx.x & 63;
    float s = 0.0f;
    for (int i = threadIdx.x; i < NBLOCKS; i += 256) s += partial[i];
#pragma unroll
    for (int m = 32; m > 0; m >>= 1) s += __shfl_xor(s, m, 64);
    __shared__ float smem[4];
    if (lane == 0) smem[threadIdx.x >> 6] = s;
    __syncthreads();
    if (threadIdx.x == 0)
        out[0] = ((smem[0] + smem[1]) + (smem[2] + smem[3])) / (float)BATCH;
}

extern "C" void kernel_launch(void* const* d_in, const int* in_sizes, int n_in,
                              void* d_out, int out_size, void* d_ws, size_t ws_size,
                              hipStream_t stream) {
    const int*   pos_x = (const int*)d_in[0];
    const int*   neg_x = (const int*)d_in[1];
    const float* ent   = (const float*)d_in[2];
    const float* entm  = (const float*)d_in[3];
    const float* rel   = (const float*)d_in[4];
    const float* relm  = (const float*)d_in[5];

    float* partial = (float*)d_ws;  // NBLOCKS floats = 32 KB
    float* out     = (float*)d_out;

    transd_score_kernel<<<NBLOCKS, 256, 0, stream>>>(pos_x, neg_x, ent, entm, rel, relm, partial);
    reduce_kernel<<<1, 256, 0, stream>>>(partial, out);
}

// Round 5
// 35.006 us; speedup vs baseline: 1.0553x; 1.0553x over previous
//
#include <hip/hip_runtime.h>
#include <stdint.h>

#define DIM 256
#define BATCH 16384
#define MARGIN 1.0f
#define EPSV 1e-6f

#define PPB 8                    // pairs per block (4 waves, 2 pairs/wave)
#define NBLOCKS (BATCH / PPB)    // 2048 blocks

typedef float fx4 __attribute__((ext_vector_type(4)));

__device__ __forceinline__ float dot4(fx4 a, fx4 b) {
    return a.x * b.x + a.y * b.y + a.z * b.z + a.w * b.w;
}

// Async global->LDS, 16B per lane. LDS dest is wave-uniform base + lane*16 (HW rule);
// global src is per-lane. One call moves one full 1KB row per wave.
__device__ __forceinline__ void gload_lds16(const void* g, void* l) {
    __builtin_amdgcn_global_load_lds(
        (const __attribute__((address_space(1))) uint32_t*)g,
        (__attribute__((address_space(3))) uint32_t*)l, 16, 0, 0);
}

// Block stages 8 pairs x 8 entity rows (h,hp,t,tp per side) = 64 rows = 64KB LDS.
// Wave w owns pairs {2w, 2w+1}: issues their 16 row-DMAs, loads their 8 relation
// rows to regs, then computes both pair losses from LDS. No cross-wave sharing.
__global__ __launch_bounds__(256, 2) void transd_loss_kernel(
    const int* __restrict__ pos_x, const int* __restrict__ neg_x,
    const float* __restrict__ ent, const float* __restrict__ entm,
    const float* __restrict__ rel, const float* __restrict__ relm,
    float* __restrict__ partial) {
    __shared__ float rows[64 * DIM];  // 64 KB
    __shared__ float wsum[4];

    const int tid  = threadIdx.x;
    const int w    = tid >> 6;
    const int lane = tid & 63;
    const int g0   = blockIdx.x * PPB;

    // --- wave-uniform indices for this wave's 2 pairs x 2 sides ---
    int hidx[2][2], ridx[2][2], tidx[2][2];
#pragma unroll
    for (int p2 = 0; p2 < 2; ++p2) {
        const int p = 2 * w + p2;
#pragma unroll
        for (int s = 0; s < 2; ++s) {
            const int* __restrict__ tri = s ? neg_x : pos_x;
            hidx[p2][s] = tri[(g0 + p) * 3 + 0];
            ridx[p2][s] = tri[(g0 + p) * 3 + 1];
            tidx[p2][s] = tri[(g0 + p) * 3 + 2];
        }
    }

    // --- issue 16 row-DMAs (4 rows per pair-side), zero data VGPRs ---
    const int lf = lane * 4;  // float offset = 16B/lane
#pragma unroll
    for (int p2 = 0; p2 < 2; ++p2) {
        const int p = 2 * w + p2;
#pragma unroll
        for (int s = 0; s < 2; ++s) {
            float* rb = &rows[(p * 8 + s * 4) * DIM];
            const size_t ho = (size_t)hidx[p2][s] * DIM + lf;
            const size_t to = (size_t)tidx[p2][s] * DIM + lf;
            gload_lds16(ent  + ho, rb + 0 * DIM);
            gload_lds16(entm + ho, rb + 1 * DIM);
            gload_lds16(ent  + to, rb + 2 * DIM);
            gload_lds16(entm + to, rb + 3 * DIM);
        }
    }

    // --- relation rows to regs (1MB tables, L2/L3-hot) ---
    fx4 rv[2][2], rpv[2][2];
#pragma unroll
    for (int p2 = 0; p2 < 2; ++p2) {
#pragma unroll
        for (int s = 0; s < 2; ++s) {
            const size_t ro = (size_t)ridx[p2][s] * DIM + lf;
            rv[p2][s]  = *(const fx4*)(rel  + ro);
            rpv[p2][s] = *(const fx4*)(relm + ro);
        }
    }

    __syncthreads();  // drains vmcnt (DMA + rel loads), then barrier

    // --- compute: 2 pairs, pos/neg interleaved shuffle chains ---
    float acc = 0.0f;
#pragma unroll
    for (int p2 = 0; p2 < 2; ++p2) {
        const int p  = 2 * w + p2;
        const float* rb0 = &rows[(p * 8 + 0) * DIM];  // pos: h,hp,t,tp
        const float* rb1 = &rows[(p * 8 + 4) * DIM];  // neg: h,hp,t,tp
        fx4 h0  = *(const fx4*)(rb0 + 0 * DIM + lf);
        fx4 hp0 = *(const fx4*)(rb0 + 1 * DIM + lf);
        fx4 t0  = *(const fx4*)(rb0 + 2 * DIM + lf);
        fx4 tp0 = *(const fx4*)(rb0 + 3 * DIM + lf);
        fx4 h1  = *(const fx4*)(rb1 + 0 * DIM + lf);
        fx4 hp1 = *(const fx4*)(rb1 + 1 * DIM + lf);
        fx4 t1  = *(const fx4*)(rb1 + 2 * DIM + lf);
        fx4 tp1 = *(const fx4*)(rb1 + 3 * DIM + lf);

        float a0 = dot4(h0, hp0), b0 = dot4(t0, tp0);
        float a1 = dot4(h1, hp1), b1 = dot4(t1, tp1);
#pragma unroll
        for (int m = 32; m > 0; m >>= 1) {
            a0 += __shfl_xor(a0, m, 64);
            b0 += __shfl_xor(b0, m, 64);
            a1 += __shfl_xor(a1, m, 64);
            b1 += __shfl_xor(b1, m, 64);
        }
        const float ab0 = a0 - b0, ab1 = a1 - b1;

        fx4 d0 = rpv[p2][0] * ab0 + h0 + rv[p2][0] - t0 + EPSV;
        fx4 d1 = rpv[p2][1] * ab1 + h1 + rv[p2][1] - t1 + EPSV;
        float ss0 = dot4(d0, d0), ss1 = dot4(d1, d1);
#pragma unroll
        for (int m = 32; m > 0; m >>= 1) {
            ss0 += __shfl_xor(ss0, m, 64);
            ss1 += __shfl_xor(ss1, m, 64);
        }
        const float v = sqrtf(ss0) - sqrtf(ss1) + MARGIN;
        acc += v > 0.0f ? v : 0.0f;
    }

    if (lane == 0) wsum[w] = acc;
    __syncthreads();
    if (tid == 0) partial[blockIdx.x] = (wsum[0] + wsum[1]) + (wsum[2] + wsum[3]);
}

// Deterministic single-block reduction of NBLOCKS floats -> out[0] = sum / BATCH.
__global__ __launch_bounds__(256) void reduce_kernel(const float* __restrict__ partial,
                                                     float* __restrict__ out) {
    const int lane = threadIdx.x & 63;
    float s = 0.0f;
    for (int i = threadIdx.x; i < NBLOCKS; i += 256) s += partial[i];
#pragma unroll
    for (int m = 32; m > 0; m >>= 1) s += __shfl_xor(s, m, 64);
    __shared__ float smem[4];
    if (lane == 0) smem[threadIdx.x >> 6] = s;
    __syncthreads();
    if (threadIdx.x == 0)
        out[0] = ((smem[0] + smem[1]) + (smem[2] + smem[3])) / (float)BATCH;
}

extern "C" void kernel_launch(void* const* d_in, const int* in_sizes, int n_in,
                              void* d_out, int out_size, void* d_ws, size_t ws_size,
                              hipStream_t stream) {
    const int*   pos_x = (const int*)d_in[0];
    const int*   neg_x = (const int*)d_in[1];
    const float* ent   = (const float*)d_in[2];
    const float* entm  = (const float*)d_in[3];
    const float* rel   = (const float*)d_in[4];
    const float* relm  = (const float*)d_in[5];

    float* partial = (float*)d_ws;  // NBLOCKS floats = 8 KB
    float* out     = (float*)d_out;

    transd_loss_kernel<<<NBLOCKS, 256, 0, stream>>>(pos_x, neg_x, ent, entm, rel, relm, partial);
    reduce_kernel<<<1, 256, 0, stream>>>(partial, out);
}